// Round 1
// baseline (785.545 us; speedup 1.0000x reference)
//
#include <hip/hip_runtime.h>
#include <hip/hip_bf16.h>
#include <hip/hip_cooperative_groups.h>

namespace cg = cooperative_groups;

// ---------------------------------------------------------------------------
// 2-layer GAT on MI355X (gfx950).  [r10: single cooperative mega-kernel]
//   Same math as r8 (best verified: 250 µs, absmax 0.0039). All 11 dispatches
//   fused into one cooperative kernel with grid.sync() phase boundaries:
//     P0 zero counts + convert W1/W2        (was memset + convWt2)
//     P1 gemm1 tiles (blocks<hb0)  ||  hist+rank (blocks>=hb0)   <- overlap
//     P2..P4 3-stage scan -> rowptr
//     P5 dst-partitioned scatter (8-way part preserved: grid % 8 == 0)
//     P6 agg1 -> A1 (bias+ReLU, bf16)
//     P7 gemm2 tiles + alpha2
//     P8 agg2 -> out
//   Grid = min(1024, occupancy*256); __launch_bounds__(256,4) + 34.8KB LDS
//   pin 4 blocks/CU so co-residency holds. Legacy multi-kernel path kept as
//   fallback if hipLaunchCooperativeKernel is refused (e.g. capture limits).
// ---------------------------------------------------------------------------

typedef __attribute__((ext_vector_type(8))) short bf16x8;
typedef __attribute__((ext_vector_type(4))) float f32x4;

#define LDS_STRIDE 136  // 128 + 8 pad (bf16): row stride 68 dwords -> 2-way max (free)
#define SCAT_CH 4096    // edges per scatter chunk (256 threads x 16)

__device__ inline unsigned short bf16bits(float v) {
    __hip_bfloat16 h = __float2bfloat16(v);
    return __builtin_bit_cast(unsigned short, h);
}
__device__ inline float bf16back(float v) {
    __hip_bfloat16 h = __float2bfloat16(v);
    return __bfloat162float(h);
}
__device__ inline float2 unpk(unsigned int u) {
    float2 r;
    r.x = __builtin_bit_cast(float, u << 16);
    r.y = __builtin_bit_cast(float, u & 0xffff0000u);
    return r;
}
__device__ inline unsigned int pk2(float a, float b) {
    return (unsigned int)bf16bits(a) | ((unsigned int)bf16bits(b) << 16);
}

// ---------------- shared device bodies (used by mega AND legacy paths) -----

__device__ __forceinline__ void gemm1_tile(int bb, const float* __restrict__ x,
                                           const unsigned short* Bs,
                                           unsigned short* __restrict__ Hb,
                                           const float* __restrict__ a_src,
                                           const float* __restrict__ a_dst,
                                           float* __restrict__ asrc,
                                           float* __restrict__ adst, int M) {
    int t = threadIdx.x;
    int wave = t >> 6, lane = t & 63;
    int m16 = lane & 15, quad = lane >> 4;
    int row0 = bb * 64 + wave * 16;
    int arow = row0 + m16;
    if (arow > M - 1) arow = M - 1;           // clamp loads; stores predicated

    f32x4 acc[8] = {};
#pragma unroll
    for (int ks = 0; ks < 4; ++ks) {
        int k0 = ks * 32 + quad * 8;
        float4 v0 = *reinterpret_cast<const float4*>(x + (size_t)arow * 128 + k0);
        float4 v1 = *reinterpret_cast<const float4*>(x + (size_t)arow * 128 + k0 + 4);
        float vv[8] = {v0.x, v0.y, v0.z, v0.w, v1.x, v1.y, v1.z, v1.w};
        union { unsigned short u[8]; bf16x8 v; } ahi, alo;
#pragma unroll
        for (int j = 0; j < 8; ++j) {
            ahi.u[j] = bf16bits(vv[j]);
            alo.u[j] = bf16bits(vv[j] - bf16back(vv[j]));
        }
#pragma unroll
        for (int nt = 0; nt < 8; ++nt) {
            bf16x8 b = __builtin_bit_cast(bf16x8,
                *reinterpret_cast<const uint4*>(&Bs[(nt * 16 + m16) * LDS_STRIDE + k0]));
            acc[nt] = __builtin_amdgcn_mfma_f32_16x16x32_bf16(alo.v, b, acc[nt], 0, 0, 0);
            acc[nt] = __builtin_amdgcn_mfma_f32_16x16x32_bf16(ahi.v, b, acc[nt], 0, 0, 0);
        }
    }
    // C/D layout: col = lane&15, row = quad*4 + reg   [m89-verified]
#pragma unroll
    for (int nt = 0; nt < 8; ++nt) {
#pragma unroll
        for (int r = 0; r < 4; ++r) {
            int gr = row0 + quad * 4 + r;
            if (gr < M) Hb[(size_t)gr * 128 + nt * 16 + m16] = bf16bits(acc[nt][r]);
        }
    }
    // fused alpha1: per (row, head) dot over 128 cols; lane holds cols nt*16+m16
    float asa[4], asb[4], ada[4], adb[4];
#pragma unroll
    for (int h = 0; h < 4; ++h) {
        asa[h] = a_src[h * 32 + m16];
        asb[h] = a_src[h * 32 + 16 + m16];
        ada[h] = a_dst[h * 32 + m16];
        adb[h] = a_dst[h * 32 + 16 + m16];
    }
#pragma unroll
    for (int r = 0; r < 4; ++r) {
        int gr = row0 + quad * 4 + r;
        float ps[4], pd[4];
#pragma unroll
        for (int h = 0; h < 4; ++h) {
            ps[h] = acc[2 * h][r] * asa[h] + acc[2 * h + 1][r] * asb[h];
            pd[h] = acc[2 * h][r] * ada[h] + acc[2 * h + 1][r] * adb[h];
        }
#pragma unroll
        for (int off = 1; off < 16; off <<= 1) {
#pragma unroll
            for (int h = 0; h < 4; ++h) {
                ps[h] += __shfl_xor(ps[h], off, 64);
                pd[h] += __shfl_xor(pd[h], off, 64);
            }
        }
        if (m16 == 0 && gr < M) {
#pragma unroll
            for (int h = 0; h < 4; ++h) {
                asrc[gr * 4 + h] = ps[h];
                adst[gr * 4 + h] = pd[h];
            }
        }
    }
}

__device__ __forceinline__ void gemm2_tile(int bb, const unsigned short* __restrict__ A1,
                                           const unsigned short* Bs,
                                           unsigned short* __restrict__ Hb,
                                           const float* __restrict__ a_src,
                                           const float* __restrict__ a_dst,
                                           float* __restrict__ asrc,
                                           float* __restrict__ adst, int M) {
    int t = threadIdx.x;
    int wave = t >> 6, lane = t & 63;
    int m16 = lane & 15, quad = lane >> 4;
    int row0 = bb * 64 + wave * 16;
    int arow = row0 + m16;
    if (arow > M - 1) arow = M - 1;

    f32x4 acc[8] = {};
#pragma unroll
    for (int ks = 0; ks < 4; ++ks) {
        int k0 = ks * 32 + quad * 8;
        bf16x8 a = __builtin_bit_cast(bf16x8,
            *reinterpret_cast<const uint4*>(A1 + (size_t)arow * 128 + k0));
#pragma unroll
        for (int nt = 0; nt < 8; ++nt) {
            bf16x8 b = __builtin_bit_cast(bf16x8,
                *reinterpret_cast<const uint4*>(&Bs[(nt * 16 + m16) * LDS_STRIDE + k0]));
            acc[nt] = __builtin_amdgcn_mfma_f32_16x16x32_bf16(a, b, acc[nt], 0, 0, 0);
        }
    }
#pragma unroll
    for (int nt = 0; nt < 8; ++nt) {
#pragma unroll
        for (int r = 0; r < 4; ++r) {
            int gr = row0 + quad * 4 + r;
            if (gr < M) Hb[(size_t)gr * 128 + nt * 16 + m16] = bf16bits(acc[nt][r]);
        }
    }
    float as2[8], ad2[8];
#pragma unroll
    for (int nt = 0; nt < 8; ++nt) {
        as2[nt] = a_src[nt * 16 + m16];
        ad2[nt] = a_dst[nt * 16 + m16];
    }
#pragma unroll
    for (int r = 0; r < 4; ++r) {
        int gr = row0 + quad * 4 + r;
        float ps = 0.f, pd = 0.f;
#pragma unroll
        for (int nt = 0; nt < 8; ++nt) {
            ps += acc[nt][r] * as2[nt];
            pd += acc[nt][r] * ad2[nt];
        }
#pragma unroll
        for (int off = 1; off < 16; off <<= 1) {
            ps += __shfl_xor(ps, off, 64);
            pd += __shfl_xor(pd, off, 64);
        }
        if (m16 == 0 && gr < M) {
            asrc[gr] = ps;
            adst[gr] = pd;
        }
    }
}

__device__ __forceinline__ void agg1_node(int d, int lane,
                                          const unsigned short* __restrict__ Hb,
                                          const float* __restrict__ asrc,
                                          const float* __restrict__ adst,
                                          const int* __restrict__ rowptr,
                                          const int* __restrict__ srcs,
                                          const float* __restrict__ bias,
                                          unsigned short* __restrict__ o1) {
    int m16 = lane & 15, quad = lane >> 4;
    int hd = m16 >> 2;
    int beg = rowptr[d], end = rowptr[d + 1];
    float adh = adst[d * 4 + hd];
    const uint4* H4 = reinterpret_cast<const uint4*>(Hb);
    float acc[8] = {};
    float den = 0.f;

    auto body = [&](int p, bool chk) {
        int ep = p + quad;
        bool valid = !chk || (ep < end);
        int se = srcs[valid ? ep : beg];
        float e = asrc[se * 4 + hd] + adh;
        e = (e > 0.f) ? e : 0.2f * e;          // leaky_relu
        float pv = __expf(e);
        if (!valid) pv = 0.f;
        den += pv;
        uint4 hv = H4[(size_t)se * 16 + m16];
        float2 f0 = unpk(hv.x), f1 = unpk(hv.y), f2 = unpk(hv.z), f3 = unpk(hv.w);
        acc[0] += pv * f0.x; acc[1] += pv * f0.y;
        acc[2] += pv * f1.x; acc[3] += pv * f1.y;
        acc[4] += pv * f2.x; acc[5] += pv * f2.y;
        acc[6] += pv * f3.x; acc[7] += pv * f3.y;
    };
    int p = beg;
    for (; p + 8 <= end; p += 8) { body(p, false); body(p + 4, false); }
    for (; p < end; p += 4) body(p, true);

#pragma unroll
    for (int off = 16; off < 64; off <<= 1) {
        den += __shfl_xor(den, off, 64);
#pragma unroll
        for (int j = 0; j < 8; ++j) acc[j] += __shfl_xor(acc[j], off, 64);
    }
    if (quad == 0) {
        float inv = 1.f / den;
        const float4* bv4 = reinterpret_cast<const float4*>(bias);
        float4 b0 = bv4[m16 * 2], b1 = bv4[m16 * 2 + 1];
        uint4 hw;
        hw.x = pk2(fmaxf(b0.x + acc[0] * inv, 0.f), fmaxf(b0.y + acc[1] * inv, 0.f));
        hw.y = pk2(fmaxf(b0.z + acc[2] * inv, 0.f), fmaxf(b0.w + acc[3] * inv, 0.f));
        hw.z = pk2(fmaxf(b1.x + acc[4] * inv, 0.f), fmaxf(b1.y + acc[5] * inv, 0.f));
        hw.w = pk2(fmaxf(b1.z + acc[6] * inv, 0.f), fmaxf(b1.w + acc[7] * inv, 0.f));
        *reinterpret_cast<uint4*>(o1 + (size_t)d * 128 + m16 * 8) = hw;
    }
}

__device__ __forceinline__ void agg2_node(int d, int lane,
                                          const unsigned short* __restrict__ Hb,
                                          const float* __restrict__ asrc,
                                          const float* __restrict__ adst,
                                          const int* __restrict__ rowptr,
                                          const int* __restrict__ srcs,
                                          const float* __restrict__ bias,
                                          float* __restrict__ out) {
    int m16 = lane & 15, quad = lane >> 4;
    int beg = rowptr[d], end = rowptr[d + 1];
    float ad = adst[d];
    const uint4* H4 = reinterpret_cast<const uint4*>(Hb);
    float acc[8] = {};
    float den = 0.f;

    auto body = [&](int p, bool chk) {
        int ep = p + quad;
        bool valid = !chk || (ep < end);
        int se = srcs[valid ? ep : beg];
        float e = asrc[se] + ad;
        e = (e > 0.f) ? e : 0.2f * e;
        float pv = __expf(e);
        if (!valid) pv = 0.f;
        den += pv;
        uint4 hv = H4[(size_t)se * 16 + m16];
        float2 f0 = unpk(hv.x), f1 = unpk(hv.y), f2 = unpk(hv.z), f3 = unpk(hv.w);
        acc[0] += pv * f0.x; acc[1] += pv * f0.y;
        acc[2] += pv * f1.x; acc[3] += pv * f1.y;
        acc[4] += pv * f2.x; acc[5] += pv * f2.y;
        acc[6] += pv * f3.x; acc[7] += pv * f3.y;
    };
    int p = beg;
    for (; p + 8 <= end; p += 8) { body(p, false); body(p + 4, false); }
    for (; p < end; p += 4) body(p, true);

#pragma unroll
    for (int off = 16; off < 64; off <<= 1) {
        den += __shfl_xor(den, off, 64);
#pragma unroll
        for (int j = 0; j < 8; ++j) acc[j] += __shfl_xor(acc[j], off, 64);
    }
    float inv = 1.f / den;
    const float4* bv4 = reinterpret_cast<const float4*>(bias);
    float4 b0 = bv4[m16 * 2], b1 = bv4[m16 * 2 + 1];
    if (quad == 0) {
        float4 o;
        o.x = b0.x + acc[0] * inv; o.y = b0.y + acc[1] * inv;
        o.z = b0.z + acc[2] * inv; o.w = b0.w + acc[3] * inv;
        *reinterpret_cast<float4*>(out + (size_t)d * 128 + m16 * 8) = o;
    }
    if (quad == 1) {
        float4 o;
        o.x = b1.x + acc[4] * inv; o.y = b1.y + acc[5] * inv;
        o.z = b1.z + acc[6] * inv; o.w = b1.w + acc[7] * inv;
        *reinterpret_cast<float4*>(out + (size_t)d * 128 + m16 * 8 + 4) = o;
    }
}

// ---------------- mega: whole pipeline, one cooperative dispatch ----------

__global__ __launch_bounds__(256, 4) void gat_mega(
    const float* __restrict__ x, const int* __restrict__ ei,
    const float* __restrict__ W1, const float* __restrict__ as1,
    const float* __restrict__ ad1, const float* __restrict__ b1,
    const float* __restrict__ W2, const float* __restrict__ as2,
    const float* __restrict__ ad2, const float* __restrict__ b2,
    float* __restrict__ out,
    unsigned short* __restrict__ A1, unsigned short* __restrict__ Hb,
    unsigned short* __restrict__ Bt1, unsigned short* __restrict__ Bt2,
    int* __restrict__ counts, int* __restrict__ rowptr,
    int* __restrict__ srcs, int* __restrict__ rank, int* __restrict__ bsum,
    float* __restrict__ asrc1, float* __restrict__ adst1,
    float* __restrict__ asrc2, float* __restrict__ adst2,
    int N, int E) {
    cg::grid_group gg = cg::this_grid();
    __shared__ unsigned short Bs[128 * LDS_STRIDE];
    __shared__ int ws4[4];
    const int t = threadIdx.x;
    const int nb = gridDim.x;
    const int gtid = blockIdx.x * 256 + t;
    const int gsz = nb * 256;
    const int tot = E + N;
    const int gtiles = (N + 63) >> 6;
    const int nchunk = (N + 255) >> 8;

    // ---- P0: zero counts + convert both weights (transpose + bf16 round) ----
    for (int i = gtid; i < N; i += gsz) counts[i] = 0;
    for (int i = gtid; i < 32768; i += gsz) {
        const float* W = (i < 16384) ? W1 : W2;
        unsigned short* Bt = (i < 16384) ? Bt1 : Bt2;
        int j = i & 16383;
        Bt[(j & 127) * 128 + (j >> 7)] = bf16bits(W[j]);
    }
    gg.sync();

    // ---- P1: gemm1 (blocks < hb0)  ||  hist+rank (blocks >= hb0) ----
    int hb0 = (nb * 3) >> 2;
    if (hb0 > gtiles) hb0 = gtiles;
    if (hb0 < 1) hb0 = 1;
    if (blockIdx.x < hb0) {
        for (int bb = blockIdx.x; bb < gtiles; bb += hb0) {
            for (int i = t; i < 128 * 16; i += 256) {
                int r = i >> 4, c = (i & 15) * 8;
                uint4 v = *reinterpret_cast<const uint4*>(Bt1 + r * 128 + c);
                *reinterpret_cast<uint4*>(&Bs[r * LDS_STRIDE + c]) = v;
            }
            __syncthreads();
            gemm1_tile(bb, x, Bs, Hb, as1, ad1, asrc1, adst1, N);
            __syncthreads();
        }
    } else {
        int ht = (blockIdx.x - hb0) * 256 + t;
        int hs = (nb - hb0) * 256;
        for (int i = ht; i < tot; i += hs) {
            int d = (i < E) ? ei[E + i] : (i - E);   // self-loops appended at end
            rank[i] = atomicAdd(&counts[d], 1);
        }
    }
    gg.sync();

    // ---- P2: scan stage A (per-chunk totals) ----
    for (int c = blockIdx.x; c < nchunk; c += nb) {
        int i = c * 256 + t;
        int v = (i < N) ? counts[i] : 0;
        for (int off = 32; off; off >>= 1) v += __shfl_down(v, off, 64);
        if ((t & 63) == 0) ws4[t >> 6] = v;
        __syncthreads();
        if (t == 0) bsum[c] = ws4[0] + ws4[1] + ws4[2] + ws4[3];
        __syncthreads();
    }
    gg.sync();

    // ---- P3: scan stage B (block 0 scans chunk totals; nchunk <= 256) ----
    if (blockIdx.x == 0) {
        int lane = t & 63, w = t >> 6;
        int orig = (t < nchunk) ? bsum[t] : 0;
        int v = orig;
        for (int off = 1; off < 64; off <<= 1) {
            int u = __shfl_up(v, off, 64);
            if (lane >= off) v += u;
        }
        if (lane == 63) ws4[w] = v;
        __syncthreads();
        int woff = 0;
        for (int i = 0; i < w; ++i) woff += ws4[i];
        if (t < nchunk) bsum[t] = woff + v - orig;   // exclusive
    }
    gg.sync();

    // ---- P4: scan stage C -> rowptr ----
    for (int c = blockIdx.x; c < nchunk; c += nb) {
        int i = c * 256 + t;
        int lane = t & 63, w = t >> 6;
        int orig = (i < N) ? counts[i] : 0;
        int v = orig;
        for (int off = 1; off < 64; off <<= 1) {
            int u = __shfl_up(v, off, 64);
            if (lane >= off) v += u;
        }
        if (lane == 63) ws4[w] = v;
        __syncthreads();
        int woff = 0;
        for (int k = 0; k < w; ++k) woff += ws4[k];
        int excl = bsum[c] + woff + v - orig;
        if (i < N) rowptr[i] = excl;
        __syncthreads();
    }
    if (gtid == 0) rowptr[N] = tot;
    gg.sync();

    // ---- P5: atomic-free dst-partitioned scatter (part = vb&7; nb%8==0
    //      keeps the XCD round-robin of the standalone kernel) ----
    const int nscat8 = ((tot + SCAT_CH - 1) / SCAT_CH) << 3;
    for (int vb = blockIdx.x; vb < nscat8; vb += nb) {
        int part = vb & 7;
        int base = (vb >> 3) * SCAT_CH;
        int thr = (N + 7) >> 3;
        int lo = part * thr;
        int hi = lo + thr; if (hi > N) hi = N;
#pragma unroll
        for (int j = 0; j < SCAT_CH / 256; ++j) {
            int i = base + j * 256 + t;
            if (i >= tot) continue;
            int d = (i < E) ? ei[E + i] : (i - E);
            if (d < lo || d >= hi) continue;
            int s = (i < E) ? ei[i] : d;
            srcs[rowptr[d] + rank[i]] = s;
        }
    }
    gg.sync();

    // ---- P6: agg1 (softmax-aggregate + bias + ReLU -> bf16 A1) ----
    const int lane = t & 63;
    const int gwid = gtid >> 6;
    const int nwv = gsz >> 6;
    for (int d = gwid; d < N; d += nwv)
        agg1_node(d, lane, Hb, asrc1, adst1, rowptr, srcs, b1, A1);
    gg.sync();

    // ---- P7: gemm2 tiles + alpha2 ----
    for (int bb = blockIdx.x; bb < gtiles; bb += nb) {
        for (int i = t; i < 128 * 16; i += 256) {
            int r = i >> 4, c = (i & 15) * 8;
            uint4 v = *reinterpret_cast<const uint4*>(Bt2 + r * 128 + c);
            *reinterpret_cast<uint4*>(&Bs[r * LDS_STRIDE + c]) = v;
        }
        __syncthreads();
        gemm2_tile(bb, A1, Bs, Hb, as2, ad2, asrc2, adst2, N);
        __syncthreads();
    }
    gg.sync();

    // ---- P8: agg2 -> out (fp32, + b2, no ReLU) ----
    for (int d = gwid; d < N; d += nwv)
        agg2_node(d, lane, Hb, asrc2, adst2, rowptr, srcs, b2, out);
}

// ---------------- legacy kernels (fallback path; same device bodies) ------

__global__ __launch_bounds__(256) void hist_rank(const int* __restrict__ ei,
                                                 int* __restrict__ counts,
                                                 int* __restrict__ rank, int E, int n) {
    int i = blockIdx.x * 256 + threadIdx.x;
    int tot = E + n;
    if (i >= tot) return;
    int d = (i < E) ? ei[E + i] : (i - E);
    int r = atomicAdd(&counts[d], 1);
    rank[i] = r;
}

__global__ __launch_bounds__(256) void scan_partial(const int* __restrict__ counts,
                                                    int* __restrict__ bsum, int n) {
    int t = threadIdx.x;
    int i = blockIdx.x * 256 + t;
    int v = (i < n) ? counts[i] : 0;
    for (int off = 32; off; off >>= 1) v += __shfl_down(v, off, 64);
    __shared__ int ws[4];
    if ((t & 63) == 0) ws[t >> 6] = v;
    __syncthreads();
    if (t == 0) bsum[blockIdx.x] = ws[0] + ws[1] + ws[2] + ws[3];
}

__global__ __launch_bounds__(256) void scan_bsums(int* __restrict__ bsum, int nb) {
    int t = threadIdx.x;
    int lane = t & 63, w = t >> 6;
    int orig = (t < nb) ? bsum[t] : 0;
    int v = orig;
    for (int off = 1; off < 64; off <<= 1) {
        int u = __shfl_up(v, off, 64);
        if (lane >= off) v += u;
    }
    __shared__ int ws[4];
    if (lane == 63) ws[w] = v;
    __syncthreads();
    int woff = 0;
    for (int i = 0; i < w; ++i) woff += ws[i];
    if (t < nb) bsum[t] = woff + v - orig;
}

__global__ __launch_bounds__(256) void scan_final(const int* __restrict__ counts,
                                                  const int* __restrict__ bsum,
                                                  int* __restrict__ rowptr, int n, int tot) {
    int t = threadIdx.x;
    int i = blockIdx.x * 256 + t;
    int lane = t & 63, w = t >> 6;
    int orig = (i < n) ? counts[i] : 0;
    int v = orig;
    for (int off = 1; off < 64; off <<= 1) {
        int u = __shfl_up(v, off, 64);
        if (lane >= off) v += u;
    }
    __shared__ int ws[4];
    if (lane == 63) ws[w] = v;
    __syncthreads();
    int woff = 0;
    for (int k = 0; k < w; ++k) woff += ws[k];
    int excl = bsum[blockIdx.x] + woff + v - orig;
    if (i < n) rowptr[i] = excl;
    if (blockIdx.x == 0 && t == 0) rowptr[n] = tot;
}

__global__ __launch_bounds__(256) void scatter_part(const int* __restrict__ ei,
                                                    const int* __restrict__ rowptr,
                                                    const int* __restrict__ rank,
                                                    int* __restrict__ srcs, int E, int n) {
    int b = blockIdx.x;
    int part = b & 7;
    int base = (b >> 3) * SCAT_CH;
    int tot = E + n;
    int thr = (n + 7) >> 3;
    int lo = part * thr;
    int hi = lo + thr; if (hi > n) hi = n;
#pragma unroll
    for (int j = 0; j < SCAT_CH / 256; ++j) {
        int i = base + j * 256 + threadIdx.x;
        if (i >= tot) continue;
        int d = (i < E) ? ei[E + i] : (i - E);
        if (d < lo || d >= hi) continue;
        int s = (i < E) ? ei[i] : d;
        srcs[rowptr[d] + rank[i]] = s;
    }
}

__global__ __launch_bounds__(256) void convWt2_kernel(const float* __restrict__ W1,
                                                      const float* __restrict__ W2,
                                                      unsigned short* __restrict__ Bt1,
                                                      unsigned short* __restrict__ Bt2) {
    int i = blockIdx.x * 256 + threadIdx.x;
    const float* W = (i < 16384) ? W1 : W2;
    unsigned short* Bt = (i < 16384) ? Bt1 : Bt2;
    int j = i & 16383;
    int k = j >> 7, n = j & 127;
    Bt[n * 128 + k] = bf16bits(W[j]);
}

__global__ __launch_bounds__(256) void gemm1_fused(const float* __restrict__ x,
                                                   const unsigned short* __restrict__ Bt,
                                                   unsigned short* __restrict__ Hb,
                                                   const float* __restrict__ a_src,
                                                   const float* __restrict__ a_dst,
                                                   float* __restrict__ asrc,
                                                   float* __restrict__ adst, int M) {
    __shared__ unsigned short Bs[128 * LDS_STRIDE];
    int t = threadIdx.x;
    for (int i = t; i < 128 * 16; i += 256) {
        int r = i >> 4, c = (i & 15) * 8;
        uint4 v = *reinterpret_cast<const uint4*>(Bt + r * 128 + c);
        *reinterpret_cast<uint4*>(&Bs[r * LDS_STRIDE + c]) = v;
    }
    __syncthreads();
    gemm1_tile(blockIdx.x, x, Bs, Hb, a_src, a_dst, asrc, adst, M);
}

__global__ __launch_bounds__(256) void gemm2_fused(const unsigned short* __restrict__ A1,
                                                   const unsigned short* __restrict__ Bt,
                                                   unsigned short* __restrict__ Hb,
                                                   const float* __restrict__ a_src,
                                                   const float* __restrict__ a_dst,
                                                   float* __restrict__ asrc,
                                                   float* __restrict__ adst, int M) {
    __shared__ unsigned short Bs[128 * LDS_STRIDE];
    int t = threadIdx.x;
    for (int i = t; i < 128 * 16; i += 256) {
        int r = i >> 4, c = (i & 15) * 8;
        uint4 v = *reinterpret_cast<const uint4*>(Bt + r * 128 + c);
        *reinterpret_cast<uint4*>(&Bs[r * LDS_STRIDE + c]) = v;
    }
    __syncthreads();
    gemm2_tile(blockIdx.x, A1, Bs, Hb, a_src, a_dst, asrc, adst, M);
}

__global__ __launch_bounds__(256) void agg1_kernel(const unsigned short* __restrict__ Hb,
                                                   const float* __restrict__ asrc,
                                                   const float* __restrict__ adst,
                                                   const int* __restrict__ rowptr,
                                                   const int* __restrict__ srcs,
                                                   const float* __restrict__ bias,
                                                   unsigned short* __restrict__ o1, int n) {
    int wid = (blockIdx.x * 256 + threadIdx.x) >> 6;
    if (wid >= n) return;
    agg1_node(wid, threadIdx.x & 63, Hb, asrc, adst, rowptr, srcs, bias, o1);
}

__global__ __launch_bounds__(256) void agg2_kernel(const unsigned short* __restrict__ Hb,
                                                   const float* __restrict__ asrc,
                                                   const float* __restrict__ adst,
                                                   const int* __restrict__ rowptr,
                                                   const int* __restrict__ srcs,
                                                   const float* __restrict__ bias,
                                                   float* __restrict__ out, int n) {
    int wid = (blockIdx.x * 256 + threadIdx.x) >> 6;
    if (wid >= n) return;
    agg2_node(wid, threadIdx.x & 63, Hb, asrc, adst, rowptr, srcs, bias, out);
}

// ---------------- launch ----------------

extern "C" void kernel_launch(void* const* d_in, const int* in_sizes, int n_in,
                              void* d_out, int out_size, void* d_ws, size_t ws_size,
                              hipStream_t stream) {
    const float* x   = (const float*)d_in[0];
    const int*   ei  = (const int*)d_in[1];
    const float* W1  = (const float*)d_in[2];
    const float* as1 = (const float*)d_in[3];
    const float* ad1 = (const float*)d_in[4];
    const float* b1  = (const float*)d_in[5];
    const float* W2  = (const float*)d_in[6];
    const float* as2 = (const float*)d_in[7];
    const float* ad2 = (const float*)d_in[8];
    const float* b2  = (const float*)d_in[9];
    float* outp = (float*)d_out;

    int N = in_sizes[0] / 128;
    int E = in_sizes[1] / 2;
    int tot = E + N;
    int nb = (N + 255) / 256;
    int nscat = (tot + SCAT_CH - 1) / SCAT_CH;

    char* wsb = (char*)d_ws;
    size_t off = 0;
    auto alloc = [&](size_t bytes) {
        void* p = wsb + off;
        off += (bytes + 255) & ~(size_t)255;
        return p;
    };
    unsigned short* A1  = (unsigned short*)alloc((size_t)N * 128 * 2);
    unsigned short* Hb  = (unsigned short*)alloc((size_t)N * 128 * 2);
    unsigned short* Bt1 = (unsigned short*)alloc(128 * 128 * 2);
    unsigned short* Bt2 = (unsigned short*)alloc(128 * 128 * 2);
    int*   counts = (int*)alloc((size_t)N * 4);
    int*   rowptr = (int*)alloc((size_t)(N + 1) * 4);
    int*   srcs   = (int*)alloc((size_t)tot * 4);
    int*   rank   = (int*)alloc((size_t)tot * 4);
    int*   bsum   = (int*)alloc(256 * 4);
    float* asrc1  = (float*)alloc((size_t)N * 4 * 4);
    float* adst1  = (float*)alloc((size_t)N * 4 * 4);
    float* asrc2  = (float*)alloc((size_t)N * 4);
    float* adst2  = (float*)alloc((size_t)N * 4);
    (void)ws_size; (void)n_in; (void)out_size;

    // ---- cooperative mega path ----
    int maxB = 0;
    hipError_t qerr = hipOccupancyMaxActiveBlocksPerMultiprocessor(&maxB, gat_mega, 256, 0);
    bool ok = false;
    if (qerr == hipSuccess && maxB > 0) {
        int grid = maxB * 256;           // 256 CUs on MI355X; always a multiple of 8
        if (grid > 1024) grid = 1024;
        void* args[] = {
            (void*)&x, (void*)&ei, (void*)&W1, (void*)&as1, (void*)&ad1, (void*)&b1,
            (void*)&W2, (void*)&as2, (void*)&ad2, (void*)&b2, (void*)&outp,
            (void*)&A1, (void*)&Hb, (void*)&Bt1, (void*)&Bt2,
            (void*)&counts, (void*)&rowptr, (void*)&srcs, (void*)&rank, (void*)&bsum,
            (void*)&asrc1, (void*)&adst1, (void*)&asrc2, (void*)&adst2,
            (void*)&N, (void*)&E};
        hipError_t lerr = hipLaunchCooperativeKernel((const void*)gat_mega, dim3(grid),
                                                     dim3(256), args, 0u, stream);
        ok = (lerr == hipSuccess);
    }
    if (ok) return;

    // ---- legacy fallback (r8 path, 11 dispatches) ----
    hipMemsetAsync(counts, 0, (size_t)N * 4, stream);
    hist_rank<<<(tot + 255) / 256, 256, 0, stream>>>(ei, counts, rank, E, N);
    scan_partial<<<nb, 256, 0, stream>>>(counts, bsum, N);
    scan_bsums<<<1, 256, 0, stream>>>(bsum, nb);
    scan_final<<<nb, 256, 0, stream>>>(counts, bsum, rowptr, N, tot);
    scatter_part<<<nscat * 8, 256, 0, stream>>>(ei, rowptr, rank, srcs, E, N);
    convWt2_kernel<<<128, 256, 0, stream>>>(W1, W2, Bt1, Bt2);

    int gblocks = (N + 63) / 64;
    gemm1_fused<<<gblocks, 256, 0, stream>>>(x, Bt1, Hb, as1, ad1, asrc1, adst1, N);
    agg1_kernel<<<(N + 3) / 4, 256, 0, stream>>>(Hb, asrc1, adst1, rowptr, srcs, b1, A1, N);
    gemm2_fused<<<gblocks, 256, 0, stream>>>(A1, Bt2, Hb, as2, ad2, asrc2, adst2, N);
    agg2_kernel<<<(N + 3) / 4, 256, 0, stream>>>(Hb, asrc2, adst2, rowptr, srcs, b2, outp, N);
}

// Round 2
// 292.528 us; speedup vs baseline: 2.6854x; 2.6854x over previous
//
#include <hip/hip_runtime.h>
#include <hip/hip_bf16.h>

// ---------------------------------------------------------------------------
// 2-layer GAT on MI355X (gfx950).  [r11: r8 structure, 7 dispatches]
//   r10 post-mortem: whole-pipeline cooperative fusion forced one occupancy
//   envelope (35KB LDS / 64 VGPR / 1024 blocks) onto all phases -> 3x
//   regression. This round keeps the proven r8 kernels/grids and only
//   removes dispatch boundaries that don't change any envelope:
//     - W1/W2 fp32->bf16 transpose done in-block inside each GEMM (conv
//       dispatch + Bt buffers removed)
//     - counts-zeroing folded into gemm1's dispatch (memset removed)
//     - 3-stage scan -> single-block 1024-thread scan (2 dispatches removed)
//   Chain: gemm1+zero -> hist -> scan1 -> scatter -> agg1 -> gemm2 -> agg2
// ---------------------------------------------------------------------------

typedef __attribute__((ext_vector_type(8))) short bf16x8;
typedef __attribute__((ext_vector_type(4))) float f32x4;

#define LDS_STRIDE 136  // 128 + 8 pad (bf16): row stride 68 dwords
#define SCAT_CH 4096    // edges per scatter block (256 threads x 16)

__device__ inline unsigned short bf16bits(float v) {
    __hip_bfloat16 h = __float2bfloat16(v);
    return __builtin_bit_cast(unsigned short, h);
}
__device__ inline float bf16back(float v) {
    __hip_bfloat16 h = __float2bfloat16(v);
    return __bfloat162float(h);
}
__device__ inline float2 unpk(unsigned int u) {
    float2 r;
    r.x = __builtin_bit_cast(float, u << 16);
    r.y = __builtin_bit_cast(float, u & 0xffff0000u);
    return r;
}
__device__ inline unsigned int pk2(float a, float b) {
    return (unsigned int)bf16bits(a) | ((unsigned int)bf16bits(b) << 16);
}

// ---------------- CSR build ----------------

__global__ __launch_bounds__(256) void hist_rank(const int* __restrict__ ei,
                                                 int* __restrict__ counts,
                                                 int* __restrict__ rank, int E, int n) {
    int i = blockIdx.x * 256 + threadIdx.x;
    int tot = E + n;
    if (i >= tot) return;
    int d = (i < E) ? ei[E + i] : (i - E);   // self-loops appended at the end
    int r = atomicAdd(&counts[d], 1);
    rank[i] = r;
}

// single-block exclusive scan: counts[0..n) -> rowptr[0..n], rowptr[n]=tot.
// 1024 threads (16 waves), 1024-wide chunks with carried offset.
__global__ __launch_bounds__(1024) void scan_block(const int* __restrict__ counts,
                                                   int* __restrict__ rowptr, int n, int tot) {
    __shared__ int wsum[16];
    __shared__ int carry_s;
    int t = threadIdx.x;
    int lane = t & 63, w = t >> 6;
    if (t == 0) carry_s = 0;
    __syncthreads();
    for (int base = 0; base < n; base += 1024) {
        int i = base + t;
        int orig = (i < n) ? counts[i] : 0;
        int v = orig;
#pragma unroll
        for (int off = 1; off < 64; off <<= 1) {
            int u = __shfl_up(v, off, 64);
            if (lane >= off) v += u;
        }
        if (lane == 63) wsum[w] = v;
        __syncthreads();
        if (t < 16) {
            int s = wsum[t];
#pragma unroll
            for (int off = 1; off < 16; off <<= 1) {
                int u = __shfl_up(s, off, 64);
                if (lane >= off) s += u;
            }
            wsum[t] = s;                       // inclusive wave-sums
        }
        __syncthreads();
        int woff = w ? wsum[w - 1] : 0;
        int excl = carry_s + woff + v - orig;
        if (i < n) rowptr[i] = excl;
        int ctot = wsum[15];
        __syncthreads();                       // all done reading carry_s/wsum
        if (t == 0) carry_s += ctot;
        __syncthreads();                       // carry visible for next chunk
    }
    if (t == 0) rowptr[n] = tot;
}

// atomic-free scatter, dst-partitioned into 8 groups (XCD swizzle: blockIdx&7)
__global__ __launch_bounds__(256) void scatter_part(const int* __restrict__ ei,
                                                    const int* __restrict__ rowptr,
                                                    const int* __restrict__ rank,
                                                    int* __restrict__ srcs, int E, int n) {
    int b = blockIdx.x;
    int part = b & 7;
    int base = (b >> 3) * SCAT_CH;
    int tot = E + n;
    int thr = (n + 7) >> 3;
    int lo = part * thr;
    int hi = lo + thr; if (hi > n) hi = n;
#pragma unroll
    for (int j = 0; j < SCAT_CH / 256; ++j) {
        int i = base + j * 256 + threadIdx.x;
        if (i >= tot) continue;
        int d = (i < E) ? ei[E + i] : (i - E);
        if (d < lo || d >= hi) continue;
        int s = (i < E) ? ei[i] : d;
        srcs[rowptr[d] + rank[i]] = s;
    }
}

// ---------------- GEMM layer 1: Hb = split(x) @ W1^T-conv, alpha1 fused ----
// In-block W conversion: Bs[n][k] = bf16(W1[k][n]); also zeroes counts[] for
// the CSR histogram (independent work folded into this dispatch).

__global__ __launch_bounds__(256) void gemm1_fused(const float* __restrict__ x,
                                                   const float* __restrict__ W1,
                                                   unsigned short* __restrict__ Hb,
                                                   const float* __restrict__ a_src,
                                                   const float* __restrict__ a_dst,
                                                   float* __restrict__ asrc,
                                                   float* __restrict__ adst,
                                                   int* __restrict__ counts,
                                                   int M, int N) {
    __shared__ unsigned short Bs[128 * LDS_STRIDE];
    int t = threadIdx.x;
    // zero counts (grid-stride; independent of GEMM)
    for (int i = blockIdx.x * 256 + t; i < N; i += gridDim.x * 256) counts[i] = 0;
    // convert W1 [k][n] fp32 -> Bs [n][k] bf16 (coalesced reads; one-time
    // 8-way LDS write conflict, ~1k cyc/block)
    for (int j = t; j < 16384; j += 256) {
        int k = j >> 7, n = j & 127;
        Bs[n * LDS_STRIDE + k] = bf16bits(W1[j]);
    }
    __syncthreads();

    int wave = t >> 6, lane = t & 63;
    int m16 = lane & 15, quad = lane >> 4;
    int row0 = blockIdx.x * 64 + wave * 16;
    int arow = row0 + m16;
    if (arow > M - 1) arow = M - 1;           // clamp loads; stores predicated

    f32x4 acc[8] = {};
#pragma unroll
    for (int ks = 0; ks < 4; ++ks) {
        int k0 = ks * 32 + quad * 8;
        float4 v0 = *reinterpret_cast<const float4*>(x + (size_t)arow * 128 + k0);
        float4 v1 = *reinterpret_cast<const float4*>(x + (size_t)arow * 128 + k0 + 4);
        float vv[8] = {v0.x, v0.y, v0.z, v0.w, v1.x, v1.y, v1.z, v1.w};
        union { unsigned short u[8]; bf16x8 v; } ahi, alo;
#pragma unroll
        for (int j = 0; j < 8; ++j) {
            ahi.u[j] = bf16bits(vv[j]);
            alo.u[j] = bf16bits(vv[j] - bf16back(vv[j]));
        }
#pragma unroll
        for (int nt = 0; nt < 8; ++nt) {
            bf16x8 b = __builtin_bit_cast(bf16x8,
                *reinterpret_cast<const uint4*>(&Bs[(nt * 16 + m16) * LDS_STRIDE + k0]));
            acc[nt] = __builtin_amdgcn_mfma_f32_16x16x32_bf16(alo.v, b, acc[nt], 0, 0, 0);
            acc[nt] = __builtin_amdgcn_mfma_f32_16x16x32_bf16(ahi.v, b, acc[nt], 0, 0, 0);
        }
    }
    // C/D layout: col = lane&15, row = quad*4 + reg   [m89-verified]
#pragma unroll
    for (int nt = 0; nt < 8; ++nt) {
#pragma unroll
        for (int r = 0; r < 4; ++r) {
            int gr = row0 + quad * 4 + r;
            if (gr < M) Hb[(size_t)gr * 128 + nt * 16 + m16] = bf16bits(acc[nt][r]);
        }
    }
    // fused alpha1: per (row, head) dot over 128 cols; lane holds cols nt*16+m16
    float asa[4], asb[4], ada[4], adb[4];
#pragma unroll
    for (int h = 0; h < 4; ++h) {
        asa[h] = a_src[h * 32 + m16];
        asb[h] = a_src[h * 32 + 16 + m16];
        ada[h] = a_dst[h * 32 + m16];
        adb[h] = a_dst[h * 32 + 16 + m16];
    }
#pragma unroll
    for (int r = 0; r < 4; ++r) {
        int gr = row0 + quad * 4 + r;
        float ps[4], pd[4];
#pragma unroll
        for (int h = 0; h < 4; ++h) {
            ps[h] = acc[2 * h][r] * asa[h] + acc[2 * h + 1][r] * asb[h];
            pd[h] = acc[2 * h][r] * ada[h] + acc[2 * h + 1][r] * adb[h];
        }
#pragma unroll
        for (int off = 1; off < 16; off <<= 1) {
#pragma unroll
            for (int h = 0; h < 4; ++h) {
                ps[h] += __shfl_xor(ps[h], off, 64);
                pd[h] += __shfl_xor(pd[h], off, 64);
            }
        }
        if (m16 == 0 && gr < M) {
#pragma unroll
            for (int h = 0; h < 4; ++h) {
                asrc[gr * 4 + h] = ps[h];
                adst[gr * 4 + h] = pd[h];
            }
        }
    }
}

// ---------------- GEMM layer 2: Hb = A1 @ W2-conv (single-term bf16) -------

__global__ __launch_bounds__(256) void gemm2_fused(const unsigned short* __restrict__ A1,
                                                   const float* __restrict__ W2,
                                                   unsigned short* __restrict__ Hb,
                                                   const float* __restrict__ a_src,
                                                   const float* __restrict__ a_dst,
                                                   float* __restrict__ asrc,
                                                   float* __restrict__ adst, int M) {
    __shared__ unsigned short Bs[128 * LDS_STRIDE];
    int t = threadIdx.x;
    for (int j = t; j < 16384; j += 256) {
        int k = j >> 7, n = j & 127;
        Bs[n * LDS_STRIDE + k] = bf16bits(W2[j]);
    }
    __syncthreads();

    int wave = t >> 6, lane = t & 63;
    int m16 = lane & 15, quad = lane >> 4;
    int row0 = blockIdx.x * 64 + wave * 16;
    int arow = row0 + m16;
    if (arow > M - 1) arow = M - 1;

    f32x4 acc[8] = {};
#pragma unroll
    for (int ks = 0; ks < 4; ++ks) {
        int k0 = ks * 32 + quad * 8;
        bf16x8 a = __builtin_bit_cast(bf16x8,
            *reinterpret_cast<const uint4*>(A1 + (size_t)arow * 128 + k0));
#pragma unroll
        for (int nt = 0; nt < 8; ++nt) {
            bf16x8 b = __builtin_bit_cast(bf16x8,
                *reinterpret_cast<const uint4*>(&Bs[(nt * 16 + m16) * LDS_STRIDE + k0]));
            acc[nt] = __builtin_amdgcn_mfma_f32_16x16x32_bf16(a, b, acc[nt], 0, 0, 0);
        }
    }
#pragma unroll
    for (int nt = 0; nt < 8; ++nt) {
#pragma unroll
        for (int r = 0; r < 4; ++r) {
            int gr = row0 + quad * 4 + r;
            if (gr < M) Hb[(size_t)gr * 128 + nt * 16 + m16] = bf16bits(acc[nt][r]);
        }
    }
    // fused alpha2: single head over 128 cols
    float as2[8], ad2[8];
#pragma unroll
    for (int nt = 0; nt < 8; ++nt) {
        as2[nt] = a_src[nt * 16 + m16];
        ad2[nt] = a_dst[nt * 16 + m16];
    }
#pragma unroll
    for (int r = 0; r < 4; ++r) {
        int gr = row0 + quad * 4 + r;
        float ps = 0.f, pd = 0.f;
#pragma unroll
        for (int nt = 0; nt < 8; ++nt) {
            ps += acc[nt][r] * as2[nt];
            pd += acc[nt][r] * ad2[nt];
        }
#pragma unroll
        for (int off = 1; off < 16; off <<= 1) {
            ps += __shfl_xor(ps, off, 64);
            pd += __shfl_xor(pd, off, 64);
        }
        if (m16 == 0 && gr < M) {
            asrc[gr] = ps;
            adst[gr] = pd;
        }
    }
}

// ---------------- aggregation ----------------
// Lane decomposition: m16 = lane&15 -> 8-channel group (16 B of the 256 B
// row); quad = lane>>4 -> edge slot. One dwordx4 gather covers 4 edges.
// Per-lane exp (no per-edge shfl); den/acc quad-reduced once per node.

__global__ __launch_bounds__(256) void agg1_kernel(const unsigned short* __restrict__ Hb,
                                                   const float* __restrict__ asrc,
                                                   const float* __restrict__ adst,
                                                   const int* __restrict__ rowptr,
                                                   const int* __restrict__ srcs,
                                                   const float* __restrict__ bias,
                                                   unsigned short* __restrict__ o1, int n) {
    int wid = (blockIdx.x * 256 + threadIdx.x) >> 6;
    int lane = threadIdx.x & 63;
    if (wid >= n) return;
    int m16 = lane & 15, quad = lane >> 4;
    int hd = m16 >> 2;
    int d = wid;
    int beg = rowptr[d], end = rowptr[d + 1];
    float adh = adst[d * 4 + hd];
    const uint4* H4 = reinterpret_cast<const uint4*>(Hb);
    float acc[8] = {};
    float den = 0.f;

    auto body = [&](int p, bool chk) {
        int ep = p + quad;
        bool valid = !chk || (ep < end);
        int se = srcs[valid ? ep : beg];
        float e = asrc[se * 4 + hd] + adh;
        e = (e > 0.f) ? e : 0.2f * e;          // leaky_relu
        float pv = __expf(e);
        if (!valid) pv = 0.f;
        den += pv;
        uint4 hv = H4[(size_t)se * 16 + m16];
        float2 f0 = unpk(hv.x), f1 = unpk(hv.y), f2 = unpk(hv.z), f3 = unpk(hv.w);
        acc[0] += pv * f0.x; acc[1] += pv * f0.y;
        acc[2] += pv * f1.x; acc[3] += pv * f1.y;
        acc[4] += pv * f2.x; acc[5] += pv * f2.y;
        acc[6] += pv * f3.x; acc[7] += pv * f3.y;
    };
    int p = beg;
    for (; p + 8 <= end; p += 8) { body(p, false); body(p + 4, false); }
    for (; p < end; p += 4) body(p, true);

#pragma unroll
    for (int off = 16; off < 64; off <<= 1) {
        den += __shfl_xor(den, off, 64);
#pragma unroll
        for (int j = 0; j < 8; ++j) acc[j] += __shfl_xor(acc[j], off, 64);
    }
    if (quad == 0) {
        float inv = 1.f / den;
        const float4* bv4 = reinterpret_cast<const float4*>(bias);
        float4 b0 = bv4[m16 * 2], b1 = bv4[m16 * 2 + 1];
        uint4 hw;
        hw.x = pk2(fmaxf(b0.x + acc[0] * inv, 0.f), fmaxf(b0.y + acc[1] * inv, 0.f));
        hw.y = pk2(fmaxf(b0.z + acc[2] * inv, 0.f), fmaxf(b0.w + acc[3] * inv, 0.f));
        hw.z = pk2(fmaxf(b1.x + acc[4] * inv, 0.f), fmaxf(b1.y + acc[5] * inv, 0.f));
        hw.w = pk2(fmaxf(b1.z + acc[6] * inv, 0.f), fmaxf(b1.w + acc[7] * inv, 0.f));
        *reinterpret_cast<uint4*>(o1 + (size_t)d * 128 + m16 * 8) = hw;
    }
}

__global__ __launch_bounds__(256) void agg2_kernel(const unsigned short* __restrict__ Hb,
                                                   const float* __restrict__ asrc,
                                                   const float* __restrict__ adst,
                                                   const int* __restrict__ rowptr,
                                                   const int* __restrict__ srcs,
                                                   const float* __restrict__ bias,
                                                   float* __restrict__ out, int n) {
    int wid = (blockIdx.x * 256 + threadIdx.x) >> 6;
    int lane = threadIdx.x & 63;
    if (wid >= n) return;
    int m16 = lane & 15, quad = lane >> 4;
    int d = wid;
    int beg = rowptr[d], end = rowptr[d + 1];
    float ad = adst[d];
    const uint4* H4 = reinterpret_cast<const uint4*>(Hb);
    float acc[8] = {};
    float den = 0.f;

    auto body = [&](int p, bool chk) {
        int ep = p + quad;
        bool valid = !chk || (ep < end);
        int se = srcs[valid ? ep : beg];
        float e = asrc[se] + ad;
        e = (e > 0.f) ? e : 0.2f * e;
        float pv = __expf(e);
        if (!valid) pv = 0.f;
        den += pv;
        uint4 hv = H4[(size_t)se * 16 + m16];
        float2 f0 = unpk(hv.x), f1 = unpk(hv.y), f2 = unpk(hv.z), f3 = unpk(hv.w);
        acc[0] += pv * f0.x; acc[1] += pv * f0.y;
        acc[2] += pv * f1.x; acc[3] += pv * f1.y;
        acc[4] += pv * f2.x; acc[5] += pv * f2.y;
        acc[6] += pv * f3.x; acc[7] += pv * f3.y;
    };
    int p = beg;
    for (; p + 8 <= end; p += 8) { body(p, false); body(p + 4, false); }
    for (; p < end; p += 4) body(p, true);

#pragma unroll
    for (int off = 16; off < 64; off <<= 1) {
        den += __shfl_xor(den, off, 64);
#pragma unroll
        for (int j = 0; j < 8; ++j) acc[j] += __shfl_xor(acc[j], off, 64);
    }
    float inv = 1.f / den;
    const float4* bv4 = reinterpret_cast<const float4*>(bias);
    float4 b0 = bv4[m16 * 2], b1 = bv4[m16 * 2 + 1];
    if (quad == 0) {
        float4 o;
        o.x = b0.x + acc[0] * inv; o.y = b0.y + acc[1] * inv;
        o.z = b0.z + acc[2] * inv; o.w = b0.w + acc[3] * inv;
        *reinterpret_cast<float4*>(out + (size_t)d * 128 + m16 * 8) = o;
    }
    if (quad == 1) {
        float4 o;
        o.x = b1.x + acc[4] * inv; o.y = b1.y + acc[5] * inv;
        o.z = b1.z + acc[6] * inv; o.w = b1.w + acc[7] * inv;
        *reinterpret_cast<float4*>(out + (size_t)d * 128 + m16 * 8 + 4) = o;
    }
}

// ---------------- launch ----------------

extern "C" void kernel_launch(void* const* d_in, const int* in_sizes, int n_in,
                              void* d_out, int out_size, void* d_ws, size_t ws_size,
                              hipStream_t stream) {
    const float* x   = (const float*)d_in[0];
    const int*   ei  = (const int*)d_in[1];
    const float* W1  = (const float*)d_in[2];
    const float* as1 = (const float*)d_in[3];
    const float* ad1 = (const float*)d_in[4];
    const float* b1  = (const float*)d_in[5];
    const float* W2  = (const float*)d_in[6];
    const float* as2 = (const float*)d_in[7];
    const float* ad2 = (const float*)d_in[8];
    const float* b2  = (const float*)d_in[9];

    int N = in_sizes[0] / 128;
    int E = in_sizes[1] / 2;
    int tot = E + N;
    int nscat = (tot + SCAT_CH - 1) / SCAT_CH;

    char* wsb = (char*)d_ws;
    size_t off = 0;
    auto alloc = [&](size_t bytes) {
        void* p = wsb + off;
        off += (bytes + 255) & ~(size_t)255;
        return p;
    };
    unsigned short* A1  = (unsigned short*)alloc((size_t)N * 128 * 2); // out1 bf16 (agg1->gemm2)
    unsigned short* Hb  = (unsigned short*)alloc((size_t)N * 128 * 2); // h bf16 (h1 then h2)
    int*   counts = (int*)alloc((size_t)N * 4);
    int*   rowptr = (int*)alloc((size_t)(N + 1) * 4);
    int*   srcs   = (int*)alloc((size_t)tot * 4);
    int*   rank   = (int*)alloc((size_t)tot * 4);
    float* asrc1  = (float*)alloc((size_t)N * 4 * 4);
    float* adst1  = (float*)alloc((size_t)N * 4 * 4);
    float* asrc2  = (float*)alloc((size_t)N * 4);
    float* adst2  = (float*)alloc((size_t)N * 4);
    (void)ws_size; (void)n_in; (void)out_size;

    int gblocks = (N + 63) / 64;

    // D1: layer-1 GEMM (in-block W1 conversion) + counts zeroing
    gemm1_fused<<<gblocks, 256, 0, stream>>>(x, W1, Hb, as1, ad1, asrc1, adst1,
                                             counts, N, N);
    // D2..D4: CSR by dst (shared by both layers)
    hist_rank<<<(tot + 255) / 256, 256, 0, stream>>>(ei, counts, rank, E, N);
    scan_block<<<1, 1024, 0, stream>>>(counts, rowptr, N, tot);
    scatter_part<<<nscat * 8, 256, 0, stream>>>(ei, rowptr, rank, srcs, E, N);

    // D5: layer-1 aggregate (softmax + bias + ReLU -> bf16 A1)
    agg1_kernel<<<(N + 3) / 4, 256, 0, stream>>>(Hb, asrc1, adst1, rowptr, srcs, b1, A1, N);

    // D6: layer-2 GEMM (in-block W2 conversion; alpha2 fused)
    gemm2_fused<<<gblocks, 256, 0, stream>>>(A1, W2, Hb, as2, ad2, asrc2, adst2, N);

    // D7: layer-2 aggregate -> out
    agg2_kernel<<<(N + 3) / 4, 256, 0, stream>>>(Hb, asrc2, adst2, rowptr, srcs, b2,
                                                 (float*)d_out, N);
}

// Round 3
// 257.172 us; speedup vs baseline: 3.0546x; 1.1375x over previous
//
#include <hip/hip_runtime.h>
#include <hip/hip_bf16.h>

// ---------------------------------------------------------------------------
// 2-layer GAT on MI355X (gfx950).  [r12: scan-free CSR]
//   r11 post-mortem: single-block scan = 48 us serialized (top dispatch).
//   Fix: eliminate the prefix-scan. Segments need not be laid out in
//   ascending-d order -- bases are allocated by a wave-parallel atomic bump
//   (in-register 64-wide scan, one atomicAdd per wave, 784 total).
//   agg uses beg=base[d], end=beg+counts[d]; scatter uses base[d]+rank[i].
//   Per-segment edge order (rank) unchanged -> bitwise-identical output.
//   Chain (7 wide dispatches):
//     gemm1+zero -> hist -> alloc -> scatter -> agg1 -> gemm2 -> agg2
// ---------------------------------------------------------------------------

typedef __attribute__((ext_vector_type(8))) short bf16x8;
typedef __attribute__((ext_vector_type(4))) float f32x4;

#define LDS_STRIDE 136  // 128 + 8 pad (bf16): row stride 68 dwords
#define SCAT_CH 4096    // edges per scatter block (256 threads x 16)

__device__ inline unsigned short bf16bits(float v) {
    __hip_bfloat16 h = __float2bfloat16(v);
    return __builtin_bit_cast(unsigned short, h);
}
__device__ inline float bf16back(float v) {
    __hip_bfloat16 h = __float2bfloat16(v);
    return __bfloat162float(h);
}
__device__ inline float2 unpk(unsigned int u) {
    float2 r;
    r.x = __builtin_bit_cast(float, u << 16);
    r.y = __builtin_bit_cast(float, u & 0xffff0000u);
    return r;
}
__device__ inline unsigned int pk2(float a, float b) {
    return (unsigned int)bf16bits(a) | ((unsigned int)bf16bits(b) << 16);
}

// ---------------- CSR build ----------------

__global__ __launch_bounds__(256) void hist_rank(const int* __restrict__ ei,
                                                 int* __restrict__ counts,
                                                 int* __restrict__ rank, int E, int n) {
    int i = blockIdx.x * 256 + threadIdx.x;
    int tot = E + n;
    if (i >= tot) return;
    int d = (i < E) ? ei[E + i] : (i - E);   // self-loops appended at the end
    int r = atomicAdd(&counts[d], 1);
    rank[i] = r;
}

// scan-free base allocation: wave-local scan + one atomic bump per wave.
// Segment order in srcs[] is arbitrary (allocation order), which is fine.
__global__ __launch_bounds__(256) void alloc_base(const int* __restrict__ counts,
                                                  int* __restrict__ base,
                                                  int* __restrict__ cursor, int n) {
    int i = blockIdx.x * 256 + threadIdx.x;
    int lane = threadIdx.x & 63;
    int v = (i < n) ? counts[i] : 0;
    int s = v;                                 // inclusive wave scan
#pragma unroll
    for (int off = 1; off < 64; off <<= 1) {
        int u = __shfl_up(s, off, 64);
        if (lane >= off) s += u;
    }
    int wbase = 0;
    if (lane == 63) wbase = atomicAdd(cursor, s);   // s = wave total at lane 63
    wbase = __shfl(wbase, 63, 64);
    if (i < n) base[i] = wbase + s - v;        // exclusive within wave + wave base
}

// atomic-free scatter, dst-partitioned into 8 groups (XCD swizzle: blockIdx&7)
__global__ __launch_bounds__(256) void scatter_part(const int* __restrict__ ei,
                                                    const int* __restrict__ base,
                                                    const int* __restrict__ rank,
                                                    int* __restrict__ srcs, int E, int n) {
    int b = blockIdx.x;
    int part = b & 7;
    int bs = (b >> 3) * SCAT_CH;
    int tot = E + n;
    int thr = (n + 7) >> 3;
    int lo = part * thr;
    int hi = lo + thr; if (hi > n) hi = n;
#pragma unroll
    for (int j = 0; j < SCAT_CH / 256; ++j) {
        int i = bs + j * 256 + threadIdx.x;
        if (i >= tot) continue;
        int d = (i < E) ? ei[E + i] : (i - E);
        if (d < lo || d >= hi) continue;
        int s = (i < E) ? ei[i] : d;
        srcs[base[d] + rank[i]] = s;
    }
}

// ---------------- GEMM layer 1: Hb = split(x) @ W1-conv, alpha1 fused ------
// In-block W conversion: Bs[n][k] = bf16(W1[k][n]); also zeroes counts[] and
// the alloc cursor (independent work folded into this dispatch).

__global__ __launch_bounds__(256) void gemm1_fused(const float* __restrict__ x,
                                                   const float* __restrict__ W1,
                                                   unsigned short* __restrict__ Hb,
                                                   const float* __restrict__ a_src,
                                                   const float* __restrict__ a_dst,
                                                   float* __restrict__ asrc,
                                                   float* __restrict__ adst,
                                                   int* __restrict__ counts,
                                                   int* __restrict__ cursor,
                                                   int M, int N) {
    __shared__ unsigned short Bs[128 * LDS_STRIDE];
    int t = threadIdx.x;
    // zero counts + cursor (grid-stride; independent of GEMM)
    for (int i = blockIdx.x * 256 + t; i < N; i += gridDim.x * 256) counts[i] = 0;
    if (blockIdx.x == 0 && t == 0) *cursor = 0;
    // convert W1 [k][n] fp32 -> Bs [n][k] bf16 (coalesced reads)
    for (int j = t; j < 16384; j += 256) {
        int k = j >> 7, n = j & 127;
        Bs[n * LDS_STRIDE + k] = bf16bits(W1[j]);
    }
    __syncthreads();

    int wave = t >> 6, lane = t & 63;
    int m16 = lane & 15, quad = lane >> 4;
    int row0 = blockIdx.x * 64 + wave * 16;
    int arow = row0 + m16;
    if (arow > M - 1) arow = M - 1;           // clamp loads; stores predicated

    f32x4 acc[8] = {};
#pragma unroll
    for (int ks = 0; ks < 4; ++ks) {
        int k0 = ks * 32 + quad * 8;
        float4 v0 = *reinterpret_cast<const float4*>(x + (size_t)arow * 128 + k0);
        float4 v1 = *reinterpret_cast<const float4*>(x + (size_t)arow * 128 + k0 + 4);
        float vv[8] = {v0.x, v0.y, v0.z, v0.w, v1.x, v1.y, v1.z, v1.w};
        union { unsigned short u[8]; bf16x8 v; } ahi, alo;
#pragma unroll
        for (int j = 0; j < 8; ++j) {
            ahi.u[j] = bf16bits(vv[j]);
            alo.u[j] = bf16bits(vv[j] - bf16back(vv[j]));
        }
#pragma unroll
        for (int nt = 0; nt < 8; ++nt) {
            bf16x8 b = __builtin_bit_cast(bf16x8,
                *reinterpret_cast<const uint4*>(&Bs[(nt * 16 + m16) * LDS_STRIDE + k0]));
            acc[nt] = __builtin_amdgcn_mfma_f32_16x16x32_bf16(alo.v, b, acc[nt], 0, 0, 0);
            acc[nt] = __builtin_amdgcn_mfma_f32_16x16x32_bf16(ahi.v, b, acc[nt], 0, 0, 0);
        }
    }
    // C/D layout: col = lane&15, row = quad*4 + reg   [m89-verified]
#pragma unroll
    for (int nt = 0; nt < 8; ++nt) {
#pragma unroll
        for (int r = 0; r < 4; ++r) {
            int gr = row0 + quad * 4 + r;
            if (gr < M) Hb[(size_t)gr * 128 + nt * 16 + m16] = bf16bits(acc[nt][r]);
        }
    }
    // fused alpha1: per (row, head) dot over 128 cols; lane holds cols nt*16+m16
    float asa[4], asb[4], ada[4], adb[4];
#pragma unroll
    for (int h = 0; h < 4; ++h) {
        asa[h] = a_src[h * 32 + m16];
        asb[h] = a_src[h * 32 + 16 + m16];
        ada[h] = a_dst[h * 32 + m16];
        adb[h] = a_dst[h * 32 + 16 + m16];
    }
#pragma unroll
    for (int r = 0; r < 4; ++r) {
        int gr = row0 + quad * 4 + r;
        float ps[4], pd[4];
#pragma unroll
        for (int h = 0; h < 4; ++h) {
            ps[h] = acc[2 * h][r] * asa[h] + acc[2 * h + 1][r] * asb[h];
            pd[h] = acc[2 * h][r] * ada[h] + acc[2 * h + 1][r] * adb[h];
        }
#pragma unroll
        for (int off = 1; off < 16; off <<= 1) {
#pragma unroll
            for (int h = 0; h < 4; ++h) {
                ps[h] += __shfl_xor(ps[h], off, 64);
                pd[h] += __shfl_xor(pd[h], off, 64);
            }
        }
        if (m16 == 0 && gr < M) {
#pragma unroll
            for (int h = 0; h < 4; ++h) {
                asrc[gr * 4 + h] = ps[h];
                adst[gr * 4 + h] = pd[h];
            }
        }
    }
}

// ---------------- GEMM layer 2: Hb = A1 @ W2-conv (single-term bf16) -------

__global__ __launch_bounds__(256) void gemm2_fused(const unsigned short* __restrict__ A1,
                                                   const float* __restrict__ W2,
                                                   unsigned short* __restrict__ Hb,
                                                   const float* __restrict__ a_src,
                                                   const float* __restrict__ a_dst,
                                                   float* __restrict__ asrc,
                                                   float* __restrict__ adst, int M) {
    __shared__ unsigned short Bs[128 * LDS_STRIDE];
    int t = threadIdx.x;
    for (int j = t; j < 16384; j += 256) {
        int k = j >> 7, n = j & 127;
        Bs[n * LDS_STRIDE + k] = bf16bits(W2[j]);
    }
    __syncthreads();

    int wave = t >> 6, lane = t & 63;
    int m16 = lane & 15, quad = lane >> 4;
    int row0 = blockIdx.x * 64 + wave * 16;
    int arow = row0 + m16;
    if (arow > M - 1) arow = M - 1;

    f32x4 acc[8] = {};
#pragma unroll
    for (int ks = 0; ks < 4; ++ks) {
        int k0 = ks * 32 + quad * 8;
        bf16x8 a = __builtin_bit_cast(bf16x8,
            *reinterpret_cast<const uint4*>(A1 + (size_t)arow * 128 + k0));
#pragma unroll
        for (int nt = 0; nt < 8; ++nt) {
            bf16x8 b = __builtin_bit_cast(bf16x8,
                *reinterpret_cast<const uint4*>(&Bs[(nt * 16 + m16) * LDS_STRIDE + k0]));
            acc[nt] = __builtin_amdgcn_mfma_f32_16x16x32_bf16(a, b, acc[nt], 0, 0, 0);
        }
    }
#pragma unroll
    for (int nt = 0; nt < 8; ++nt) {
#pragma unroll
        for (int r = 0; r < 4; ++r) {
            int gr = row0 + quad * 4 + r;
            if (gr < M) Hb[(size_t)gr * 128 + nt * 16 + m16] = bf16bits(acc[nt][r]);
        }
    }
    // fused alpha2: single head over 128 cols
    float as2[8], ad2[8];
#pragma unroll
    for (int nt = 0; nt < 8; ++nt) {
        as2[nt] = a_src[nt * 16 + m16];
        ad2[nt] = a_dst[nt * 16 + m16];
    }
#pragma unroll
    for (int r = 0; r < 4; ++r) {
        int gr = row0 + quad * 4 + r;
        float ps = 0.f, pd = 0.f;
#pragma unroll
        for (int nt = 0; nt < 8; ++nt) {
            ps += acc[nt][r] * as2[nt];
            pd += acc[nt][r] * ad2[nt];
        }
#pragma unroll
        for (int off = 1; off < 16; off <<= 1) {
            ps += __shfl_xor(ps, off, 64);
            pd += __shfl_xor(pd, off, 64);
        }
        if (m16 == 0 && gr < M) {
            asrc[gr] = ps;
            adst[gr] = pd;
        }
    }
}

// ---------------- aggregation ----------------
// Lane decomposition: m16 = lane&15 -> 8-channel group (16 B of the 256 B
// row); quad = lane>>4 -> edge slot. One dwordx4 gather covers 4 edges.
// Per-lane exp (no per-edge shfl); den/acc quad-reduced once per node.

__global__ __launch_bounds__(256) void agg1_kernel(const unsigned short* __restrict__ Hb,
                                                   const float* __restrict__ asrc,
                                                   const float* __restrict__ adst,
                                                   const int* __restrict__ base,
                                                   const int* __restrict__ counts,
                                                   const int* __restrict__ srcs,
                                                   const float* __restrict__ bias,
                                                   unsigned short* __restrict__ o1, int n) {
    int wid = (blockIdx.x * 256 + threadIdx.x) >> 6;
    int lane = threadIdx.x & 63;
    if (wid >= n) return;
    int m16 = lane & 15, quad = lane >> 4;
    int hd = m16 >> 2;
    int d = wid;
    int beg = base[d], end = beg + counts[d];
    float adh = adst[d * 4 + hd];
    const uint4* H4 = reinterpret_cast<const uint4*>(Hb);
    float acc[8] = {};
    float den = 0.f;

    auto body = [&](int p, bool chk) {
        int ep = p + quad;
        bool valid = !chk || (ep < end);
        int se = srcs[valid ? ep : beg];
        float e = asrc[se * 4 + hd] + adh;
        e = (e > 0.f) ? e : 0.2f * e;          // leaky_relu
        float pv = __expf(e);
        if (!valid) pv = 0.f;
        den += pv;
        uint4 hv = H4[(size_t)se * 16 + m16];
        float2 f0 = unpk(hv.x), f1 = unpk(hv.y), f2 = unpk(hv.z), f3 = unpk(hv.w);
        acc[0] += pv * f0.x; acc[1] += pv * f0.y;
        acc[2] += pv * f1.x; acc[3] += pv * f1.y;
        acc[4] += pv * f2.x; acc[5] += pv * f2.y;
        acc[6] += pv * f3.x; acc[7] += pv * f3.y;
    };
    int p = beg;
    for (; p + 8 <= end; p += 8) { body(p, false); body(p + 4, false); }
    for (; p < end; p += 4) body(p, true);

#pragma unroll
    for (int off = 16; off < 64; off <<= 1) {
        den += __shfl_xor(den, off, 64);
#pragma unroll
        for (int j = 0; j < 8; ++j) acc[j] += __shfl_xor(acc[j], off, 64);
    }
    if (quad == 0) {
        float inv = 1.f / den;
        const float4* bv4 = reinterpret_cast<const float4*>(bias);
        float4 b0 = bv4[m16 * 2], b1 = bv4[m16 * 2 + 1];
        uint4 hw;
        hw.x = pk2(fmaxf(b0.x + acc[0] * inv, 0.f), fmaxf(b0.y + acc[1] * inv, 0.f));
        hw.y = pk2(fmaxf(b0.z + acc[2] * inv, 0.f), fmaxf(b0.w + acc[3] * inv, 0.f));
        hw.z = pk2(fmaxf(b1.x + acc[4] * inv, 0.f), fmaxf(b1.y + acc[5] * inv, 0.f));
        hw.w = pk2(fmaxf(b1.z + acc[6] * inv, 0.f), fmaxf(b1.w + acc[7] * inv, 0.f));
        *reinterpret_cast<uint4*>(o1 + (size_t)d * 128 + m16 * 8) = hw;
    }
}

__global__ __launch_bounds__(256) void agg2_kernel(const unsigned short* __restrict__ Hb,
                                                   const float* __restrict__ asrc,
                                                   const float* __restrict__ adst,
                                                   const int* __restrict__ base,
                                                   const int* __restrict__ counts,
                                                   const int* __restrict__ srcs,
                                                   const float* __restrict__ bias,
                                                   float* __restrict__ out, int n) {
    int wid = (blockIdx.x * 256 + threadIdx.x) >> 6;
    int lane = threadIdx.x & 63;
    if (wid >= n) return;
    int m16 = lane & 15, quad = lane >> 4;
    int d = wid;
    int beg = base[d], end = beg + counts[d];
    float ad = adst[d];
    const uint4* H4 = reinterpret_cast<const uint4*>(Hb);
    float acc[8] = {};
    float den = 0.f;

    auto body = [&](int p, bool chk) {
        int ep = p + quad;
        bool valid = !chk || (ep < end);
        int se = srcs[valid ? ep : beg];
        float e = asrc[se] + ad;
        e = (e > 0.f) ? e : 0.2f * e;
        float pv = __expf(e);
        if (!valid) pv = 0.f;
        den += pv;
        uint4 hv = H4[(size_t)se * 16 + m16];
        float2 f0 = unpk(hv.x), f1 = unpk(hv.y), f2 = unpk(hv.z), f3 = unpk(hv.w);
        acc[0] += pv * f0.x; acc[1] += pv * f0.y;
        acc[2] += pv * f1.x; acc[3] += pv * f1.y;
        acc[4] += pv * f2.x; acc[5] += pv * f2.y;
        acc[6] += pv * f3.x; acc[7] += pv * f3.y;
    };
    int p = beg;
    for (; p + 8 <= end; p += 8) { body(p, false); body(p + 4, false); }
    for (; p < end; p += 4) body(p, true);

#pragma unroll
    for (int off = 16; off < 64; off <<= 1) {
        den += __shfl_xor(den, off, 64);
#pragma unroll
        for (int j = 0; j < 8; ++j) acc[j] += __shfl_xor(acc[j], off, 64);
    }
    float inv = 1.f / den;
    const float4* bv4 = reinterpret_cast<const float4*>(bias);
    float4 b0 = bv4[m16 * 2], b1 = bv4[m16 * 2 + 1];
    if (quad == 0) {
        float4 o;
        o.x = b0.x + acc[0] * inv; o.y = b0.y + acc[1] * inv;
        o.z = b0.z + acc[2] * inv; o.w = b0.w + acc[3] * inv;
        *reinterpret_cast<float4*>(out + (size_t)d * 128 + m16 * 8) = o;
    }
    if (quad == 1) {
        float4 o;
        o.x = b1.x + acc[4] * inv; o.y = b1.y + acc[5] * inv;
        o.z = b1.z + acc[6] * inv; o.w = b1.w + acc[7] * inv;
        *reinterpret_cast<float4*>(out + (size_t)d * 128 + m16 * 8 + 4) = o;
    }
}

// ---------------- launch ----------------

extern "C" void kernel_launch(void* const* d_in, const int* in_sizes, int n_in,
                              void* d_out, int out_size, void* d_ws, size_t ws_size,
                              hipStream_t stream) {
    const float* x   = (const float*)d_in[0];
    const int*   ei  = (const int*)d_in[1];
    const float* W1  = (const float*)d_in[2];
    const float* as1 = (const float*)d_in[3];
    const float* ad1 = (const float*)d_in[4];
    const float* b1  = (const float*)d_in[5];
    const float* W2  = (const float*)d_in[6];
    const float* as2 = (const float*)d_in[7];
    const float* ad2 = (const float*)d_in[8];
    const float* b2  = (const float*)d_in[9];

    int N = in_sizes[0] / 128;
    int E = in_sizes[1] / 2;
    int tot = E + N;
    int nscat = (tot + SCAT_CH - 1) / SCAT_CH;

    char* wsb = (char*)d_ws;
    size_t off = 0;
    auto alloc = [&](size_t bytes) {
        void* p = wsb + off;
        off += (bytes + 255) & ~(size_t)255;
        return p;
    };
    unsigned short* A1  = (unsigned short*)alloc((size_t)N * 128 * 2); // out1 bf16 (agg1->gemm2)
    unsigned short* Hb  = (unsigned short*)alloc((size_t)N * 128 * 2); // h bf16 (h1 then h2)
    int*   counts = (int*)alloc((size_t)N * 4);
    int*   base   = (int*)alloc((size_t)N * 4);
    int*   srcs   = (int*)alloc((size_t)tot * 4);
    int*   rank   = (int*)alloc((size_t)tot * 4);
    int*   cursor = (int*)alloc(256);
    float* asrc1  = (float*)alloc((size_t)N * 4 * 4);
    float* adst1  = (float*)alloc((size_t)N * 4 * 4);
    float* asrc2  = (float*)alloc((size_t)N * 4);
    float* adst2  = (float*)alloc((size_t)N * 4);
    (void)ws_size; (void)n_in; (void)out_size;

    int gblocks = (N + 63) / 64;

    // D1: layer-1 GEMM (in-block W1 conversion) + counts/cursor zeroing
    gemm1_fused<<<gblocks, 256, 0, stream>>>(x, W1, Hb, as1, ad1, asrc1, adst1,
                                             counts, cursor, N, N);
    // D2..D4: CSR by dst (scan-free; shared by both layers)
    hist_rank<<<(tot + 255) / 256, 256, 0, stream>>>(ei, counts, rank, E, N);
    alloc_base<<<(N + 255) / 256, 256, 0, stream>>>(counts, base, cursor, N);
    scatter_part<<<nscat * 8, 256, 0, stream>>>(ei, base, rank, srcs, E, N);

    // D5: layer-1 aggregate (softmax + bias + ReLU -> bf16 A1)
    agg1_kernel<<<(N + 3) / 4, 256, 0, stream>>>(Hb, asrc1, adst1, base, counts,
                                                 srcs, b1, A1, N);
    // D6: layer-2 GEMM (in-block W2 conversion; alpha2 fused)
    gemm2_fused<<<gblocks, 256, 0, stream>>>(A1, W2, Hb, as2, ad2, asrc2, adst2, N);

    // D7: layer-2 aggregate -> out
    agg2_kernel<<<(N + 3) / 4, 256, 0, stream>>>(Hb, asrc2, adst2, base, counts,
                                                 srcs, b2, (float*)d_out, N);
}

// Round 4
// 252.819 us; speedup vs baseline: 3.1071x; 1.0172x over previous
//
#include <hip/hip_runtime.h>
#include <hip/hip_bf16.h>

// ---------------------------------------------------------------------------
// 2-layer GAT on MI355X (gfx950).  [r13: hoisted W-conv + deeper agg ILP]
//   r12 post-mortem: in-GEMM W conversion (r11 fusion) cost ~+6-12 us --
//   782 blocks each re-reading 64KB fp32 W + scalar transposed LDS writes.
//   Kernel time dominates, not launch gaps -> hoist conversion back to a
//   tiny prep dispatch; GEMMs stage 32KB bf16 Bt from L2 (r8 style).
//   agg main loop unrolled 2->4 gathers in flight (16 edges/iter; avg
//   degree 16.8). Per-lane accumulation order unchanged -> bitwise output.
//   Chain (8 dispatches):
//     prep(zero+conv) -> gemm1 -> hist -> alloc -> scatter -> agg1
//       -> gemm2 -> agg2
// ---------------------------------------------------------------------------

typedef __attribute__((ext_vector_type(8))) short bf16x8;
typedef __attribute__((ext_vector_type(4))) float f32x4;

#define LDS_STRIDE 136  // 128 + 8 pad (bf16): row stride 68 dwords
#define SCAT_CH 4096    // edges per scatter block (256 threads x 16)

__device__ inline unsigned short bf16bits(float v) {
    __hip_bfloat16 h = __float2bfloat16(v);
    return __builtin_bit_cast(unsigned short, h);
}
__device__ inline float bf16back(float v) {
    __hip_bfloat16 h = __float2bfloat16(v);
    return __bfloat162float(h);
}
__device__ inline float2 unpk(unsigned int u) {
    float2 r;
    r.x = __builtin_bit_cast(float, u << 16);
    r.y = __builtin_bit_cast(float, u & 0xffff0000u);
    return r;
}
__device__ inline unsigned int pk2(float a, float b) {
    return (unsigned int)bf16bits(a) | ((unsigned int)bf16bits(b) << 16);
}

// ---------------- prep: zero counts/cursor + convert both weights ----------
// W [128 K][128 N] fp32 -> Bt [128 N][128 K] bf16 (transpose+round), once.

__global__ __launch_bounds__(256) void prep_kernel(const float* __restrict__ W1,
                                                   const float* __restrict__ W2,
                                                   unsigned short* __restrict__ Bt1,
                                                   unsigned short* __restrict__ Bt2,
                                                   int* __restrict__ counts,
                                                   int* __restrict__ cursor, int n) {
    int i = blockIdx.x * 256 + threadIdx.x;
    int gs = gridDim.x * 256;
    for (int j = i; j < n; j += gs) counts[j] = 0;
    if (i == 0) *cursor = 0;
    for (int j = i; j < 32768; j += gs) {
        const float* W = (j < 16384) ? W1 : W2;
        unsigned short* Bt = (j < 16384) ? Bt1 : Bt2;
        int q = j & 16383;
        Bt[(q & 127) * 128 + (q >> 7)] = bf16bits(W[q]);
    }
}

// ---------------- CSR build ----------------

__global__ __launch_bounds__(256) void hist_rank(const int* __restrict__ ei,
                                                 int* __restrict__ counts,
                                                 int* __restrict__ rank, int E, int n) {
    int i = blockIdx.x * 256 + threadIdx.x;
    int tot = E + n;
    if (i >= tot) return;
    int d = (i < E) ? ei[E + i] : (i - E);   // self-loops appended at the end
    int r = atomicAdd(&counts[d], 1);
    rank[i] = r;
}

// scan-free base allocation: wave-local scan + one atomic bump per wave.
__global__ __launch_bounds__(256) void alloc_base(const int* __restrict__ counts,
                                                  int* __restrict__ base,
                                                  int* __restrict__ cursor, int n) {
    int i = blockIdx.x * 256 + threadIdx.x;
    int lane = threadIdx.x & 63;
    int v = (i < n) ? counts[i] : 0;
    int s = v;                                 // inclusive wave scan
#pragma unroll
    for (int off = 1; off < 64; off <<= 1) {
        int u = __shfl_up(s, off, 64);
        if (lane >= off) s += u;
    }
    int wbase = 0;
    if (lane == 63) wbase = atomicAdd(cursor, s);   // s = wave total at lane 63
    wbase = __shfl(wbase, 63, 64);
    if (i < n) base[i] = wbase + s - v;        // exclusive within wave + wave base
}

// atomic-free scatter, dst-partitioned into 8 groups (XCD swizzle: blockIdx&7)
__global__ __launch_bounds__(256) void scatter_part(const int* __restrict__ ei,
                                                    const int* __restrict__ base,
                                                    const int* __restrict__ rank,
                                                    int* __restrict__ srcs, int E, int n) {
    int b = blockIdx.x;
    int part = b & 7;
    int bs = (b >> 3) * SCAT_CH;
    int tot = E + n;
    int thr = (n + 7) >> 3;
    int lo = part * thr;
    int hi = lo + thr; if (hi > n) hi = n;
#pragma unroll
    for (int j = 0; j < SCAT_CH / 256; ++j) {
        int i = bs + j * 256 + threadIdx.x;
        if (i >= tot) continue;
        int d = (i < E) ? ei[E + i] : (i - E);
        if (d < lo || d >= hi) continue;
        int s = (i < E) ? ei[i] : d;
        srcs[base[d] + rank[i]] = s;
    }
}

// ---------------- GEMM layer 1: Hb = split(x) @ B1, alpha1 fused ----------

__global__ __launch_bounds__(256) void gemm1_fused(const float* __restrict__ x,
                                                   const unsigned short* __restrict__ Bt,
                                                   unsigned short* __restrict__ Hb,
                                                   const float* __restrict__ a_src,
                                                   const float* __restrict__ a_dst,
                                                   float* __restrict__ asrc,
                                                   float* __restrict__ adst, int M) {
    __shared__ unsigned short Bs[128 * LDS_STRIDE];
    int t = threadIdx.x;
    for (int i = t; i < 128 * 16; i += 256) {
        int r = i >> 4, c = (i & 15) * 8;
        uint4 v = *reinterpret_cast<const uint4*>(Bt + r * 128 + c);
        *reinterpret_cast<uint4*>(&Bs[r * LDS_STRIDE + c]) = v;
    }
    __syncthreads();

    int wave = t >> 6, lane = t & 63;
    int m16 = lane & 15, quad = lane >> 4;
    int row0 = blockIdx.x * 64 + wave * 16;
    int arow = row0 + m16;
    if (arow > M - 1) arow = M - 1;           // clamp loads; stores predicated

    f32x4 acc[8] = {};
#pragma unroll
    for (int ks = 0; ks < 4; ++ks) {
        int k0 = ks * 32 + quad * 8;
        float4 v0 = *reinterpret_cast<const float4*>(x + (size_t)arow * 128 + k0);
        float4 v1 = *reinterpret_cast<const float4*>(x + (size_t)arow * 128 + k0 + 4);
        float vv[8] = {v0.x, v0.y, v0.z, v0.w, v1.x, v1.y, v1.z, v1.w};
        union { unsigned short u[8]; bf16x8 v; } ahi, alo;
#pragma unroll
        for (int j = 0; j < 8; ++j) {
            ahi.u[j] = bf16bits(vv[j]);
            alo.u[j] = bf16bits(vv[j] - bf16back(vv[j]));
        }
#pragma unroll
        for (int nt = 0; nt < 8; ++nt) {
            bf16x8 b = __builtin_bit_cast(bf16x8,
                *reinterpret_cast<const uint4*>(&Bs[(nt * 16 + m16) * LDS_STRIDE + k0]));
            acc[nt] = __builtin_amdgcn_mfma_f32_16x16x32_bf16(alo.v, b, acc[nt], 0, 0, 0);
            acc[nt] = __builtin_amdgcn_mfma_f32_16x16x32_bf16(ahi.v, b, acc[nt], 0, 0, 0);
        }
    }
    // C/D layout: col = lane&15, row = quad*4 + reg   [m89-verified]
#pragma unroll
    for (int nt = 0; nt < 8; ++nt) {
#pragma unroll
        for (int r = 0; r < 4; ++r) {
            int gr = row0 + quad * 4 + r;
            if (gr < M) Hb[(size_t)gr * 128 + nt * 16 + m16] = bf16bits(acc[nt][r]);
        }
    }
    // fused alpha1: per (row, head) dot over 128 cols; lane holds cols nt*16+m16
    float asa[4], asb[4], ada[4], adb[4];
#pragma unroll
    for (int h = 0; h < 4; ++h) {
        asa[h] = a_src[h * 32 + m16];
        asb[h] = a_src[h * 32 + 16 + m16];
        ada[h] = a_dst[h * 32 + m16];
        adb[h] = a_dst[h * 32 + 16 + m16];
    }
#pragma unroll
    for (int r = 0; r < 4; ++r) {
        int gr = row0 + quad * 4 + r;
        float ps[4], pd[4];
#pragma unroll
        for (int h = 0; h < 4; ++h) {
            ps[h] = acc[2 * h][r] * asa[h] + acc[2 * h + 1][r] * asb[h];
            pd[h] = acc[2 * h][r] * ada[h] + acc[2 * h + 1][r] * adb[h];
        }
#pragma unroll
        for (int off = 1; off < 16; off <<= 1) {
#pragma unroll
            for (int h = 0; h < 4; ++h) {
                ps[h] += __shfl_xor(ps[h], off, 64);
                pd[h] += __shfl_xor(pd[h], off, 64);
            }
        }
        if (m16 == 0 && gr < M) {
#pragma unroll
            for (int h = 0; h < 4; ++h) {
                asrc[gr * 4 + h] = ps[h];
                adst[gr * 4 + h] = pd[h];
            }
        }
    }
}

// ---------------- GEMM layer 2: Hb = A1 @ B2 (single-term bf16), alpha2 ----

__global__ __launch_bounds__(256) void gemm2_fused(const unsigned short* __restrict__ A1,
                                                   const unsigned short* __restrict__ Bt,
                                                   unsigned short* __restrict__ Hb,
                                                   const float* __restrict__ a_src,
                                                   const float* __restrict__ a_dst,
                                                   float* __restrict__ asrc,
                                                   float* __restrict__ adst, int M) {
    __shared__ unsigned short Bs[128 * LDS_STRIDE];
    int t = threadIdx.x;
    for (int i = t; i < 128 * 16; i += 256) {
        int r = i >> 4, c = (i & 15) * 8;
        uint4 v = *reinterpret_cast<const uint4*>(Bt + r * 128 + c);
        *reinterpret_cast<uint4*>(&Bs[r * LDS_STRIDE + c]) = v;
    }
    __syncthreads();

    int wave = t >> 6, lane = t & 63;
    int m16 = lane & 15, quad = lane >> 4;
    int row0 = blockIdx.x * 64 + wave * 16;
    int arow = row0 + m16;
    if (arow > M - 1) arow = M - 1;

    f32x4 acc[8] = {};
#pragma unroll
    for (int ks = 0; ks < 4; ++ks) {
        int k0 = ks * 32 + quad * 8;
        bf16x8 a = __builtin_bit_cast(bf16x8,
            *reinterpret_cast<const uint4*>(A1 + (size_t)arow * 128 + k0));
#pragma unroll
        for (int nt = 0; nt < 8; ++nt) {
            bf16x8 b = __builtin_bit_cast(bf16x8,
                *reinterpret_cast<const uint4*>(&Bs[(nt * 16 + m16) * LDS_STRIDE + k0]));
            acc[nt] = __builtin_amdgcn_mfma_f32_16x16x32_bf16(a, b, acc[nt], 0, 0, 0);
        }
    }
#pragma unroll
    for (int nt = 0; nt < 8; ++nt) {
#pragma unroll
        for (int r = 0; r < 4; ++r) {
            int gr = row0 + quad * 4 + r;
            if (gr < M) Hb[(size_t)gr * 128 + nt * 16 + m16] = bf16bits(acc[nt][r]);
        }
    }
    // fused alpha2: single head over 128 cols
    float as2[8], ad2[8];
#pragma unroll
    for (int nt = 0; nt < 8; ++nt) {
        as2[nt] = a_src[nt * 16 + m16];
        ad2[nt] = a_dst[nt * 16 + m16];
    }
#pragma unroll
    for (int r = 0; r < 4; ++r) {
        int gr = row0 + quad * 4 + r;
        float ps = 0.f, pd = 0.f;
#pragma unroll
        for (int nt = 0; nt < 8; ++nt) {
            ps += acc[nt][r] * as2[nt];
            pd += acc[nt][r] * ad2[nt];
        }
#pragma unroll
        for (int off = 1; off < 16; off <<= 1) {
            ps += __shfl_xor(ps, off, 64);
            pd += __shfl_xor(pd, off, 64);
        }
        if (m16 == 0 && gr < M) {
            asrc[gr] = ps;
            adst[gr] = pd;
        }
    }
}

// ---------------- aggregation ----------------
// Lane decomposition: m16 = lane&15 -> 8-channel group (16 B of the 256 B
// row); quad = lane>>4 -> edge slot. One dwordx4 gather covers 4 edges.
// Main loop keeps 4 row-gathers in flight (16 edges/iter, avg degree 16.8).
// Per-lane accumulation order identical to 2-deep version -> bitwise output.

__global__ __launch_bounds__(256) void agg1_kernel(const unsigned short* __restrict__ Hb,
                                                   const float* __restrict__ asrc,
                                                   const float* __restrict__ adst,
                                                   const int* __restrict__ base,
                                                   const int* __restrict__ counts,
                                                   const int* __restrict__ srcs,
                                                   const float* __restrict__ bias,
                                                   unsigned short* __restrict__ o1, int n) {
    int wid = (blockIdx.x * 256 + threadIdx.x) >> 6;
    int lane = threadIdx.x & 63;
    if (wid >= n) return;
    int m16 = lane & 15, quad = lane >> 4;
    int hd = m16 >> 2;
    int d = wid;
    int beg = base[d], end = beg + counts[d];
    float adh = adst[d * 4 + hd];
    const uint4* H4 = reinterpret_cast<const uint4*>(Hb);
    float acc[8] = {};
    float den = 0.f;

    auto body = [&](int p, bool chk) {
        int ep = p + quad;
        bool valid = !chk || (ep < end);
        int se = srcs[valid ? ep : beg];
        float e = asrc[se * 4 + hd] + adh;
        e = (e > 0.f) ? e : 0.2f * e;          // leaky_relu
        float pv = __expf(e);
        if (!valid) pv = 0.f;
        den += pv;
        uint4 hv = H4[(size_t)se * 16 + m16];
        float2 f0 = unpk(hv.x), f1 = unpk(hv.y), f2 = unpk(hv.z), f3 = unpk(hv.w);
        acc[0] += pv * f0.x; acc[1] += pv * f0.y;
        acc[2] += pv * f1.x; acc[3] += pv * f1.y;
        acc[4] += pv * f2.x; acc[5] += pv * f2.y;
        acc[6] += pv * f3.x; acc[7] += pv * f3.y;
    };
    int p = beg;
    for (; p + 16 <= end; p += 16) {
        body(p, false); body(p + 4, false); body(p + 8, false); body(p + 12, false);
    }
    for (; p + 8 <= end; p += 8) { body(p, false); body(p + 4, false); }
    for (; p < end; p += 4) body(p, true);

#pragma unroll
    for (int off = 16; off < 64; off <<= 1) {
        den += __shfl_xor(den, off, 64);
#pragma unroll
        for (int j = 0; j < 8; ++j) acc[j] += __shfl_xor(acc[j], off, 64);
    }
    if (quad == 0) {
        float inv = 1.f / den;
        const float4* bv4 = reinterpret_cast<const float4*>(bias);
        float4 b0 = bv4[m16 * 2], b1 = bv4[m16 * 2 + 1];
        uint4 hw;
        hw.x = pk2(fmaxf(b0.x + acc[0] * inv, 0.f), fmaxf(b0.y + acc[1] * inv, 0.f));
        hw.y = pk2(fmaxf(b0.z + acc[2] * inv, 0.f), fmaxf(b0.w + acc[3] * inv, 0.f));
        hw.z = pk2(fmaxf(b1.x + acc[4] * inv, 0.f), fmaxf(b1.y + acc[5] * inv, 0.f));
        hw.w = pk2(fmaxf(b1.z + acc[6] * inv, 0.f), fmaxf(b1.w + acc[7] * inv, 0.f));
        *reinterpret_cast<uint4*>(o1 + (size_t)d * 128 + m16 * 8) = hw;
    }
}

__global__ __launch_bounds__(256) void agg2_kernel(const unsigned short* __restrict__ Hb,
                                                   const float* __restrict__ asrc,
                                                   const float* __restrict__ adst,
                                                   const int* __restrict__ base,
                                                   const int* __restrict__ counts,
                                                   const int* __restrict__ srcs,
                                                   const float* __restrict__ bias,
                                                   float* __restrict__ out, int n) {
    int wid = (blockIdx.x * 256 + threadIdx.x) >> 6;
    int lane = threadIdx.x & 63;
    if (wid >= n) return;
    int m16 = lane & 15, quad = lane >> 4;
    int d = wid;
    int beg = base[d], end = beg + counts[d];
    float ad = adst[d];
    const uint4* H4 = reinterpret_cast<const uint4*>(Hb);
    float acc[8] = {};
    float den = 0.f;

    auto body = [&](int p, bool chk) {
        int ep = p + quad;
        bool valid = !chk || (ep < end);
        int se = srcs[valid ? ep : beg];
        float e = asrc[se] + ad;
        e = (e > 0.f) ? e : 0.2f * e;
        float pv = __expf(e);
        if (!valid) pv = 0.f;
        den += pv;
        uint4 hv = H4[(size_t)se * 16 + m16];
        float2 f0 = unpk(hv.x), f1 = unpk(hv.y), f2 = unpk(hv.z), f3 = unpk(hv.w);
        acc[0] += pv * f0.x; acc[1] += pv * f0.y;
        acc[2] += pv * f1.x; acc[3] += pv * f1.y;
        acc[4] += pv * f2.x; acc[5] += pv * f2.y;
        acc[6] += pv * f3.x; acc[7] += pv * f3.y;
    };
    int p = beg;
    for (; p + 16 <= end; p += 16) {
        body(p, false); body(p + 4, false); body(p + 8, false); body(p + 12, false);
    }
    for (; p + 8 <= end; p += 8) { body(p, false); body(p + 4, false); }
    for (; p < end; p += 4) body(p, true);

#pragma unroll
    for (int off = 16; off < 64; off <<= 1) {
        den += __shfl_xor(den, off, 64);
#pragma unroll
        for (int j = 0; j < 8; ++j) acc[j] += __shfl_xor(acc[j], off, 64);
    }
    float inv = 1.f / den;
    const float4* bv4 = reinterpret_cast<const float4*>(bias);
    float4 b0 = bv4[m16 * 2], b1 = bv4[m16 * 2 + 1];
    if (quad == 0) {
        float4 o;
        o.x = b0.x + acc[0] * inv; o.y = b0.y + acc[1] * inv;
        o.z = b0.z + acc[2] * inv; o.w = b0.w + acc[3] * inv;
        *reinterpret_cast<float4*>(out + (size_t)d * 128 + m16 * 8) = o;
    }
    if (quad == 1) {
        float4 o;
        o.x = b1.x + acc[4] * inv; o.y = b1.y + acc[5] * inv;
        o.z = b1.z + acc[6] * inv; o.w = b1.w + acc[7] * inv;
        *reinterpret_cast<float4*>(out + (size_t)d * 128 + m16 * 8 + 4) = o;
    }
}

// ---------------- launch ----------------

extern "C" void kernel_launch(void* const* d_in, const int* in_sizes, int n_in,
                              void* d_out, int out_size, void* d_ws, size_t ws_size,
                              hipStream_t stream) {
    const float* x   = (const float*)d_in[0];
    const int*   ei  = (const int*)d_in[1];
    const float* W1  = (const float*)d_in[2];
    const float* as1 = (const float*)d_in[3];
    const float* ad1 = (const float*)d_in[4];
    const float* b1  = (const float*)d_in[5];
    const float* W2  = (const float*)d_in[6];
    const float* as2 = (const float*)d_in[7];
    const float* ad2 = (const float*)d_in[8];
    const float* b2  = (const float*)d_in[9];

    int N = in_sizes[0] / 128;
    int E = in_sizes[1] / 2;
    int tot = E + N;
    int nscat = (tot + SCAT_CH - 1) / SCAT_CH;

    char* wsb = (char*)d_ws;
    size_t off = 0;
    auto alloc = [&](size_t bytes) {
        void* p = wsb + off;
        off += (bytes + 255) & ~(size_t)255;
        return p;
    };
    unsigned short* A1  = (unsigned short*)alloc((size_t)N * 128 * 2); // out1 bf16 (agg1->gemm2)
    unsigned short* Hb  = (unsigned short*)alloc((size_t)N * 128 * 2); // h bf16 (h1 then h2)
    unsigned short* Bt1 = (unsigned short*)alloc(128 * 128 * 2);
    unsigned short* Bt2 = (unsigned short*)alloc(128 * 128 * 2);
    int*   counts = (int*)alloc((size_t)N * 4);
    int*   base   = (int*)alloc((size_t)N * 4);
    int*   srcs   = (int*)alloc((size_t)tot * 4);
    int*   rank   = (int*)alloc((size_t)tot * 4);
    int*   cursor = (int*)alloc(256);
    float* asrc1  = (float*)alloc((size_t)N * 4 * 4);
    float* adst1  = (float*)alloc((size_t)N * 4 * 4);
    float* asrc2  = (float*)alloc((size_t)N * 4);
    float* adst2  = (float*)alloc((size_t)N * 4);
    (void)ws_size; (void)n_in; (void)out_size;

    int gblocks = (N + 63) / 64;

    // D1: prep (zero counts/cursor; convert W1,W2 -> Bt1,Bt2 once)
    prep_kernel<<<128, 256, 0, stream>>>(W1, W2, Bt1, Bt2, counts, cursor, N);

    // D2: layer-1 GEMM (stages 32KB bf16 Bt1; alpha1 fused)
    gemm1_fused<<<gblocks, 256, 0, stream>>>(x, Bt1, Hb, as1, ad1, asrc1, adst1, N);

    // D3..D5: CSR by dst (scan-free; shared by both layers)
    hist_rank<<<(tot + 255) / 256, 256, 0, stream>>>(ei, counts, rank, E, N);
    alloc_base<<<(N + 255) / 256, 256, 0, stream>>>(counts, base, cursor, N);
    scatter_part<<<nscat * 8, 256, 0, stream>>>(ei, base, rank, srcs, E, N);

    // D6: layer-1 aggregate (softmax + bias + ReLU -> bf16 A1)
    agg1_kernel<<<(N + 3) / 4, 256, 0, stream>>>(Hb, asrc1, adst1, base, counts,
                                                 srcs, b1, A1, N);
    // D7: layer-2 GEMM (alpha2 fused)
    gemm2_fused<<<gblocks, 256, 0, stream>>>(A1, Bt2, Hb, as2, ad2, asrc2, adst2, N);

    // D8: layer-2 aggregate -> out
    agg2_kernel<<<(N + 3) / 4, 256, 0, stream>>>(Hb, asrc2, adst2, base, counts,
                                                 srcs, b2, (float*)d_out, N);
}